// Round 1
// baseline (59.929 us; speedup 1.0000x reference)
//
#include <hip/hip_runtime.h>

// TreeMapping: DEPTH=8, N_NODES=255, N_LEAVES=256, BATCH=512.
//
// Mask matrices encode root-to-node paths of a complete binary tree in heap
// layout; every output is a product of <=8 factors x[b,i] or (1-x[b,i]).
// Leaf l's path bits are the binary digits of l (MSB first).
//
// THIS ROUND: probe whether the ~20us above the harness poison-fill floor is
// kernel-side. 4 rows per 256-thread block (one wave64 per row, grid 512->128),
// each lane owns 4 consecutive leaves:
//   depths 0..5: lane-indexed factors, prefix product C (published node probs)
//   depth 6:     factor from x6 = xs[63+lane]            (bit = j>>1)
//   depth 7:     factors from x7a/x7b = xs[127+2*lane +{0,1}] (bit = j&1)
// Leaves written as one coalesced float4 per lane. Depth-6/7 node probs are
// C, C*x6, C*(1-x6) -- unconditional stores, no predication.
// Multiply order is ascending depth, matching jnp.prod -> absmax 0.0.
//
// Output layout: d_out = leaf_probs[512][256] ++ node_probs[512][255].

#define TM_BATCH    512
#define TM_N_NODES  255
#define TM_N_LEAVES 256
#define TM_ROWS_PB  4      // rows per block (1 per wave64)

__global__ __launch_bounds__(256)
void TreeMapping_67671504715946_kernel(const float* __restrict__ x,
                                       float* __restrict__ out) {
    __shared__ float xs[TM_ROWS_PB][TM_N_LEAVES];   // 4 KiB
    const int t    = threadIdx.x;
    const int rr   = t >> 6;          // row-within-block = wave id
    const int lane = t & 63;
    const int row  = blockIdx.x * TM_ROWS_PB + rr;

    // Stage this wave's row (coalesced 64-lane bursts).
    const float* __restrict__ xrow = x + row * TM_N_NODES;
#pragma unroll
    for (int k = 0; k < 4; ++k) {
        const int idx = lane + 64 * k;
        if (idx < TM_N_NODES) xs[rr][idx] = xrow[idx];
    }
    __syncthreads();

    float* __restrict__ leaf_out = out + row * TM_N_LEAVES;
    float* __restrict__ node_out = out + TM_BATCH * TM_N_LEAVES + row * TM_N_NODES;

    // Depths 0..5: ancestor index (1<<d)-1 + (lane >> (6-d)); independent LDS
    // reads (broadcast / 2-way at most). Publish node prob (prefix BEFORE the
    // depth-d factor) from the single lane per node with low (6-d) bits zero.
    float p = 1.0f;
#pragma unroll
    for (int d = 0; d < 6; ++d) {
        const int i = (1 << d) - 1 + (lane >> (6 - d));
        const float xv = xs[rr][i];
        if ((lane & ((64 >> d) - 1)) == 0) node_out[i] = p;
        const int bit = (lane >> (5 - d)) & 1;
        p *= bit ? (1.0f - xv) : xv;    // v_cndmask + v_mul, no divergence
    }
    const float C = p;                   // prefix through depth 5

    const float x6  = xs[rr][63 + lane];          // depth-6 ancestor (1/lane)
    const float x7a = xs[rr][127 + 2 * lane];     // depth-7 ancestors (2/lane)
    const float x7b = xs[rr][128 + 2 * lane];

    node_out[63 + lane] = C;                      // depth-6 node prob
    const float C6a = C * x6;                     // prefix for leaves j=0,1
    const float C6b = C * (1.0f - x6);            // prefix for leaves j=2,3
    node_out[127 + 2 * lane] = C6a;               // depth-7 node probs
    node_out[128 + 2 * lane] = C6b;

    float4 lv;                                    // leaves 4*lane .. 4*lane+3
    lv.x = C6a * x7a;
    lv.y = C6a * (1.0f - x7a);
    lv.z = C6b * x7b;
    lv.w = C6b * (1.0f - x7b);
    *reinterpret_cast<float4*>(leaf_out + 4 * lane) = lv;
}

extern "C" void kernel_launch(void* const* d_in, const int* in_sizes, int n_in,
                              void* d_out, int out_size, void* d_ws, size_t ws_size,
                              hipStream_t stream) {
    const float* x = (const float*)d_in[0];   // (512, 255) fp32
    // d_in[1..3] (mask matrices) are implied by the tree structure; unused.
    float* out = (float*)d_out;               // 512*256 + 512*255 fp32

    TreeMapping_67671504715946_kernel<<<TM_BATCH / TM_ROWS_PB, 256, 0, stream>>>(x, out);
}